// Round 10
// baseline (2017.026 us; speedup 1.0000x reference)
//
#include <hip/hip_runtime.h>
#include <stdint.h>

typedef unsigned short u16;
typedef unsigned int   u32;
typedef __attribute__((ext_vector_type(8))) short short8;
typedef __attribute__((ext_vector_type(4))) float f32x4;
typedef __attribute__((ext_vector_type(4))) u32   u32x4;

#define AS1 __attribute__((address_space(1)))
#define AS3 __attribute__((address_space(3)))

#define SENT 0x7FC0u   // bf16 NaN sentinel: unreachable by f2bf of finite |h|<1.05
#define HS   528       // hBl batch-row stride in u16: 1056B -> 2-way banks (free)

__device__ __forceinline__ float bf2f(u16 u) {
  union { u32 i; float f; } v; v.i = ((u32)u) << 16; return v.f;
}
__device__ __forceinline__ u16 f2bf(float f) {
  union { float f; u32 i; } v; v.f = f;
  u32 i = v.i;
  i += 0x7FFFu + ((i >> 16) & 1u);   // round-to-nearest-even
  return (u16)(i >> 16);
}
__device__ __forceinline__ float tanh_fast(float x) {
  const float e = __expf(-2.f * fabsf(x));
  const float t = (1.f - e) / (1.f + e);
  return __builtin_copysignf(t, x);
}

__device__ __forceinline__ void gload16(const u16* src, u16* ldsDst) {
  __builtin_amdgcn_global_load_lds((const AS1 u32*)src, (AS3 u32*)ldsDst, 16, 0, 0);
}

// ---- MALL-coherent (cache-bypassing) h exchange — PROVEN protocol ----------
// s_waitcnt INSIDE the asm: LLVM's waitcnt pass does not model asm VMEM ops.
__device__ __forceinline__ short8 ldg_sc_h_wait(const u16* p) {
  short8 r;
  asm volatile("global_load_dwordx4 %0, %1, off sc0 sc1\n\t"
               "s_waitcnt vmcnt(0)"
               : "=v"(r) : "v"(p) : "memory");
  return r;
}
__device__ __forceinline__ void stg_sc_h(u16* p, u16 v) {
  asm volatile("global_store_short %0, %1, off sc0 sc1" :: "v"(p), "v"((u32)v) : "memory");
}

// ---------------- init: pad+cast x ------------------------------------------
__global__ void k_init(const float* __restrict__ x, u16* __restrict__ xp) {
  const long NXP = 32L * 576 * 512;
  long i0 = (long)blockIdx.x * 256 + threadIdx.x;
  for (long i = i0; i < NXP; i += (long)gridDim.x * 256) {
    long b = i / (576 * 512);
    int rem = (int)(i - b * (576 * 512));
    int rr = rem >> 9, dd = rem & 511;
    int t = rr - 31;                       // SAME pad: 31 left, 33 right
    float v = (t >= 0 && t < 512) ? x[(b * 512 + t) * 512 + dd] : 0.f;
    xp[i] = f2bf(v);
  }
}

// ---------------- sentinel fill of hstep (16.77 MB) --------------------------
__global__ void k_sent(u32* __restrict__ hs) {
  const u32x4 s = u32x4{(SENT << 16) | SENT, (SENT << 16) | SENT,
                        (SENT << 16) | SENT, (SENT << 16) | SENT};
  *(u32x4*)&hs[((long)blockIdx.x * 256 + threadIdx.x) * 4] = s;
}

// ---------------- transpose + cast fp32 -> bf16 ------------------------------
__global__ void k_transpose_cast(const float* __restrict__ in, u16* __restrict__ out,
                                 int rows, int cols, long inWStride, long outWStride) {
  __shared__ float tile[64][65];
  const int w = blockIdx.z;
  const float* ip = in + (long)w * inWStride;
  u16* op = out + (long)w * outWStride;
  const int r0 = blockIdx.y * 64, c0 = blockIdx.x * 64;
  const int tr = threadIdx.x >> 6, tc = threadIdx.x & 63;
  #pragma unroll
  for (int p = 0; p < 16; ++p) {
    int rr = p * 4 + tr;
    tile[rr][tc] = ip[(long)(r0 + rr) * cols + c0 + tc];
  }
  __syncthreads();
  #pragma unroll
  for (int p = 0; p < 16; ++p) {
    int rr = p * 4 + tr;
    op[(long)(c0 + rr) * rows + r0 + tc] = f2bf(tile[tc][rr]);
  }
}

// ---------------- conv GEMM: sliding-window A reuse + B prefetch pipeline ----
// z[row, h] = sum_w sum_d xp[row+w, d] * fT[w, h, d].
// A panel (192 x 64) staged once per d-chunk (8x/block). B double-buffered:
// next phase's 4 gloads issued BEFORE this phase's MFMA (T3 minimal 2-phase) --
// staging latency hides under MFMA+ds_read; end-of-phase barrier drains.
__global__ __launch_bounds__(256) void k_conv(
    const u16* __restrict__ A, const u16* __restrict__ Bm, u16* __restrict__ C)
{
  __shared__ __align__(16) u16 Abig[192 * 64];      // 24.6 KB
  __shared__ __align__(16) u16 Blds[2][128 * 64];   // 2 x 16.4 KB
  const int bid0 = blockIdx.x;
  const int bid = (bid0 & 7) * 64 + (bid0 >> 3);    // XCD-bijective (512 % 8 == 0)
  const int mt = bid & 127, nt = bid >> 7;          // same-B blocks share an XCD chunk
  const int bb = (mt * 128) >> 9;
  const int t0 = (mt * 128) & 511;
  const int h0 = nt * 128;
  const int tid = threadIdx.x;
  const int wv = tid >> 6, l = tid & 63;
  const int wr = wv >> 1, wc = wv & 1;
  const int sRow = wv * 8 + (l >> 3);
  const int sCol = (l & 7) * 8;
  f32x4 acc[4][4];
  #pragma unroll
  for (int m = 0; m < 4; ++m)
    #pragma unroll
    for (int n = 0; n < 4; ++n) acc[m][n] = f32x4{0.f, 0.f, 0.f, 0.f};

  const long aRow0 = (long)(bb * 576 + t0);         // rows t0..t0+191 fit pitch 576

  auto stageB = [&](int p, int buf) {
    const int ds = p >> 6, w = p & 63;
    const u16* bB = Bm + ((long)w << 18) + (long)h0 * 512 + (ds << 6) + sCol;
    #pragma unroll
    for (int c = 0; c < 4; ++c)
      gload16(bB + (long)(c * 32 + sRow) * 512, &Blds[buf][(c * 32 + wv * 8) * 64]);
  };

  stageB(0, 0);                                     // prologue
  for (int p = 0; p < 512; ++p) {
    const int dsub = p >> 6, w = p & 63, cur = p & 1;
    if (w == 0) {
      // A panel for this dsub; prior barrier guarantees Abig readers done.
      #pragma unroll
      for (int c = 0; c < 6; ++c)
        gload16(A + (aRow0 + c * 32 + sRow) * 512 + (dsub << 6) + sCol,
                &Abig[(c * 32 + wv * 8) * 64]);
      __syncthreads();                              // drain A (and pending B)
    }
    if (p < 511) stageB(p + 1, cur ^ 1);            // prefetch next B (other buffer)
    #pragma unroll
    for (int kk = 0; kk < 2; ++kk) {
      short8 af[4], bf[4];
      #pragma unroll
      for (int m = 0; m < 4; ++m)
        af[m] = *(const short8*)&Abig[(w + wr * 64 + m * 16 + (l & 15)) * 64 + kk * 32 + (l >> 4) * 8];
      #pragma unroll
      for (int n = 0; n < 4; ++n)
        bf[n] = *(const short8*)&Blds[cur][(wc * 64 + n * 16 + (l & 15)) * 64 + kk * 32 + (l >> 4) * 8];
      #pragma unroll
      for (int m = 0; m < 4; ++m)
        #pragma unroll
        for (int n = 0; n < 4; ++n)
          acc[m][n] = __builtin_amdgcn_mfma_f32_16x16x32_bf16(af[m], bf[n], acc[m][n], 0, 0, 0);
    }
    __syncthreads();   // drains next-B staging; orders Blds reuse & Abig overwrite
  }
  const int lr = (l >> 4) * 4, lc = l & 15;
  #pragma unroll
  for (int m = 0; m < 4; ++m)
    #pragma unroll
    for (int n = 0; n < 4; ++n)
      #pragma unroll
      for (int r = 0; r < 4; ++r) {
        const int row = mt * 128 + wr * 64 + m * 16 + lr + r;
        const int col = h0 + wc * 64 + n * 16 + lc;
        C[(long)row * 512 + col] = f2bf(tanhf(acc[m][n][r]));
      }
}

// ---------------- tiled MFMA GEMM (XM = x @ gru_kernel) ----------------------
__global__ __launch_bounds__(256) void k_gemm(
    const u16* __restrict__ A, const u16* __restrict__ Bm, u16* __restrict__ C,
    int nTiles, int kw, int woff, long bWStride, int outMode)
{
  __shared__ __align__(16) u16 Alds[128 * 64];
  __shared__ __align__(16) u16 Blds[128 * 64];
  const int bid0 = blockIdx.x;
  const int cpx = gridDim.x >> 3;
  const int bid = (bid0 & 7) * cpx + (bid0 >> 3);
  const int mt = bid / nTiles, nt = bid - mt * nTiles;
  const int bb = (mt * 128) >> 9;
  const int t0 = (mt * 128) & 511;
  const int h0 = nt * 128;
  const int tid = threadIdx.x;
  const int wv = tid >> 6, l = tid & 63;
  const int wr = wv >> 1, wc = wv & 1;
  const int sRow = wv * 8 + (l >> 3);
  const int sCol = (l & 7) * 8;
  f32x4 acc[4][4];
  #pragma unroll
  for (int m = 0; m < 4; ++m)
    #pragma unroll
    for (int n = 0; n < 4; ++n) acc[m][n] = f32x4{0.f, 0.f, 0.f, 0.f};

  const int kIters = kw * 8;
  const long aRow0 = (long)(bb * 576 + t0 + woff);
  for (int q = 0; q < kIters; ++q) {
    const int w = q >> 3, dsub = (q & 7) << 6;
    const u16* aB = A + (aRow0 + w) * 512 + dsub + sCol;
    const u16* bB = Bm + (long)w * bWStride + (long)h0 * 512 + dsub + sCol;
    __syncthreads();
    #pragma unroll
    for (int c = 0; c < 4; ++c) {
      gload16(aB + (long)(c * 32 + sRow) * 512, &Alds[c * 2048 + wv * 512]);
      gload16(bB + (long)(c * 32 + sRow) * 512, &Blds[c * 2048 + wv * 512]);
    }
    __syncthreads();
    #pragma unroll
    for (int kk = 0; kk < 2; ++kk) {
      short8 af[4], bf[4];
      #pragma unroll
      for (int m = 0; m < 4; ++m)
        af[m] = *(const short8*)&Alds[(wr * 64 + m * 16 + (l & 15)) * 64 + kk * 32 + (l >> 4) * 8];
      #pragma unroll
      for (int n = 0; n < 4; ++n)
        bf[n] = *(const short8*)&Blds[(wc * 64 + n * 16 + (l & 15)) * 64 + kk * 32 + (l >> 4) * 8];
      #pragma unroll
      for (int m = 0; m < 4; ++m)
        #pragma unroll
        for (int n = 0; n < 4; ++n)
          acc[m][n] = __builtin_amdgcn_mfma_f32_16x16x32_bf16(af[m], bf[n], acc[m][n], 0, 0, 0);
    }
  }
  const int lr = (l >> 4) * 4, lc = l & 15;
  #pragma unroll
  for (int m = 0; m < 4; ++m)
    #pragma unroll
    for (int n = 0; n < 4; ++n)
      #pragma unroll
      for (int r = 0; r < 4; ++r) {
        const int row = mt * 128 + wr * 64 + m * 16 + lr + r;
        const int col = h0 + wc * 64 + n * 16 + lc;
        const float v = acc[m][n][r];
        if (outMode == 0) {
          C[(long)row * 512 + col] = f2bf(tanhf(v));
        } else {
          const int b = row >> 9, t = row & 511;
          C[((long)t * 32 + b) * 1536 + col] = f2bf(v);
        }
      }
}

// ---------------- dza[t][b] = za(b,t,:)·wd2 + (g1-g0) -----------------------
__global__ void k_dza(const u16* __restrict__ za, const float* __restrict__ fskip,
                      const float* __restrict__ ug, float* __restrict__ dza) {
  __shared__ float wd2[512];
  const int t = blockIdx.x, tid = threadIdx.x;
  for (int i = tid; i < 512; i += 256) wd2[i] = fskip[(512 + i) * 2 + 1] - fskip[(512 + i) * 2];
  __syncthreads();
  const int b = tid >> 3, seg = (tid & 7) * 64;
  const u16* row = za + ((long)b * 512 + t) * 512 + seg;
  float pp = 0.f;
  #pragma unroll
  for (int j = 0; j < 8; ++j) {
    short8 v = *(const short8*)&row[j * 8];
    #pragma unroll
    for (int e = 0; e < 8; ++e) pp += bf2f((u16)v[e]) * wd2[seg + j * 8 + e];
  }
  pp += __shfl_xor(pp, 1); pp += __shfl_xor(pp, 2); pp += __shfl_xor(pp, 4);
  if ((tid & 7) == 0) {
    float u0 = ug[((long)t * 32 + b) * 2 + 0], u1 = ug[((long)t * 32 + b) * 2 + 1];
    float g0 = -logf(-logf(u0 + 1e-20f) + 1e-20f);
    float g1 = -logf(-logf(u1 + 1e-20f) + 1e-20f);
    dza[t * 32 + b] = pp + (g1 - g0);
  }
}

// ---------------- persistent recurrence: 8 domains x 8 slices ---------------
// EXACT round-7 protocol (proven 1273 us): MALL data-is-flag, padded LDS,
// delayed out-store, post-poll XM prefetch. DO NOT TOUCH.
__global__ __launch_bounds__(256, 1) void k_rnn(
    const u16* __restrict__ XM, const float* __restrict__ dza,
    const float* __restrict__ Wrec, const float* __restrict__ gbias,
    const float* __restrict__ fskip, u16* hstep, float* __restrict__ out)
{
  const int bid = blockIdx.x, d = bid & 7, s = bid >> 3;
  const int tid = threadIdx.x, wv = tid >> 6, l = tid & 63;
  __shared__ __align__(16) u16 hBl[2][4 * HS];
  __shared__ float s1s[2][4];

  float wdv[8];
  #pragma unroll
  for (int e = 0; e < 8; ++e)
    wdv[e] = fskip[(l * 8 + e) * 2 + 1] - fskip[(l * 8 + e) * 2];

  const int colb = s * 64 + wv * 16 + (l & 15);
  const int kq = (l >> 4) * 8;

  short8 wf[3][16];
  #pragma unroll
  for (int g = 0; g < 3; ++g)
    #pragma unroll
    for (int kk = 0; kk < 16; ++kk) {
      short8 tmp;
      #pragma unroll
      for (int e = 0; e < 8; ++e)
        tmp[e] = (short)f2bf(Wrec[(long)(kk * 32 + kq + e) * 1536 + g * 512 + colb]);
      wf[g][kk] = tmp;
    }
  float bi[3], br[3];
  #pragma unroll
  for (int g = 0; g < 3; ++g) {
    bi[g] = gbias[g * 512 + colb];
    br[g] = gbias[1536 + g * 512 + colb];
  }
  const int myb = d * 4;
  float hp[4] = {0.f, 0.f, 0.f, 0.f};
  float hnv[4] = {0.f, 0.f, 0.f, 0.f};

  u16 xmc[3][4];
  float dzc;
  if (l < 16) {
    const u16* xr = XM + (long)myb * 1536;
    #pragma unroll
    for (int r = 0; r < 4; ++r)
      #pragma unroll
      for (int g = 0; g < 3; ++g)
        xmc[g][r] = xr[(long)r * 1536 + g * 512 + colb];
  }
  dzc = dza[myb + wv];

  for (int t = 0; t < 512; ++t) {
    const int p = t & 1;

    short8 h8;
    if (t > 0) {
      const u16* ph = hstep + ((long)(t - 1) * 32 + myb + wv) * 512 + l * 8;
      h8 = ldg_sc_h_wait(ph);
      bool bad = true;
      while (bad) {
        bad = false;
        #pragma unroll
        for (int e = 0; e < 8; ++e) bad |= ((u16)h8[e] == SENT);
        if (bad) h8 = ldg_sc_h_wait(ph);
      }
    } else {
      #pragma unroll
      for (int e = 0; e < 8; ++e) h8[e] = 0;
    }

    if (t > 0 && l < 16) {
      #pragma unroll
      for (int r = 0; r < 4; ++r)
        out[((long)(myb + r) * 512 + (t - 1)) * 512 + colb] = hnv[r];
    }

    u16 xmn[3][4];
    const int tn = (t < 511) ? t + 1 : t;
    if (l < 16) {
      const u16* xr = XM + ((long)tn * 32 + myb) * 1536;
      #pragma unroll
      for (int r = 0; r < 4; ++r)
        #pragma unroll
        for (int g = 0; g < 3; ++g)
          xmn[g][r] = xr[(long)r * 1536 + g * 512 + colb];
    }
    const float dzn = dza[tn * 32 + myb + wv];

    *(short8*)&hBl[p][wv * HS + l * 8] = h8;
    float pp = 0.f;
    #pragma unroll
    for (int e = 0; e < 8; ++e) pp += bf2f((u16)h8[e]) * wdv[e];
    #pragma unroll
    for (int o = 1; o < 64; o <<= 1) pp += __shfl_xor(pp, o);
    if (l == 0) s1s[p][wv] = 1.f / (1.f + __expf(-(pp + dzc)));
    __syncthreads();

    f32x4 acc[3];
    acc[0] = f32x4{0.f, 0.f, 0.f, 0.f}; acc[1] = acc[0]; acc[2] = acc[0];
    const int b4 = l & 3;
    #pragma unroll
    for (int kk = 0; kk < 16; ++kk) {
      short8 a = *(const short8*)&hBl[p][b4 * HS + kk * 32 + kq];
      acc[0] = __builtin_amdgcn_mfma_f32_16x16x32_bf16(a, wf[0][kk], acc[0], 0, 0, 0);
      acc[1] = __builtin_amdgcn_mfma_f32_16x16x32_bf16(a, wf[1][kk], acc[1], 0, 0, 0);
      acc[2] = __builtin_amdgcn_mfma_f32_16x16x32_bf16(a, wf[2][kk], acc[2], 0, 0, 0);
    }

    if (l < 16) {
      #pragma unroll
      for (int r = 0; r < 4; ++r) {
        const float xz = bf2f(xmc[0][r]) + bi[0];
        const float xr_ = bf2f(xmc[1][r]) + bi[1];
        const float xh = bf2f(xmc[2][r]) + bi[2];
        const float hz = acc[0][r] + br[0];
        const float hr = acc[1][r] + br[1];
        const float hh = acc[2][r] + br[2];
        const float z  = 1.f / (1.f + __expf(-(xz + hz)));
        const float rr = 1.f / (1.f + __expf(-(xr_ + hr)));
        const float hc = tanh_fast(xh + rr * hh);
        const float ht = z * hp[r] + (1.f - z) * hc;
        const float s1 = s1s[p][r];
        const float hn = hp[r] + s1 * (ht - hp[r]);
        stg_sc_h(&hstep[((long)t * 32 + myb + r) * 512 + colb], f2bf(hn));
        hp[r] = hn;
        hnv[r] = hn;
      }
      #pragma unroll
      for (int g = 0; g < 3; ++g)
        #pragma unroll
        for (int r = 0; r < 4; ++r) xmc[g][r] = xmn[g][r];
    }
    dzc = dzn;
  }
  if (l < 16) {
    #pragma unroll
    for (int r = 0; r < 4; ++r)
      out[((long)(myb + r) * 512 + 511) * 512 + colb] = hnv[r];
  }
}

// -----------------------------------------------------------------------------
extern "C" void kernel_launch(void* const* d_in, const int* in_sizes, int n_in,
                              void* d_out, int out_size, void* d_ws, size_t ws_size,
                              hipStream_t stream) {
  (void)in_sizes; (void)n_in; (void)out_size; (void)ws_size;
  const float* x        = (const float*)d_in[0];
  const float* f_after  = (const float*)d_in[1];
  const float* f_skip   = (const float*)d_in[2];
  const float* gru_k    = (const float*)d_in[3];
  const float* gru_rec  = (const float*)d_in[4];
  const float* gru_bias = (const float*)d_in[5];
  const float* ug       = (const float*)d_in[6];
  float* out = (float*)d_out;

  char* ws = (char*)d_ws;
  size_t off = 0;
  auto alloc = [&](size_t bytes) { void* p = ws + off; off = (off + bytes + 255) & ~(size_t)255; return p; };
  u16*  xp    = (u16*)alloc(32L * 576 * 512 * 2);
  u16*  fT    = (u16*)alloc(64L * 512 * 512 * 2);
  u16*  gruT  = (u16*)alloc(1536L * 512 * 2);
  u16*  za    = (u16*)alloc(32L * 512 * 512 * 2);   // reused as hstep after k_dza
  u16*  XM    = (u16*)alloc(512L * 32 * 1536 * 2);
  float* dza  = (float*)alloc(512L * 32 * 4);
  u16*  hstep = za;                                  // [512][32][512] bf16

  k_init<<<dim3(4096), dim3(256), 0, stream>>>(x, xp);
  k_transpose_cast<<<dim3(8, 8, 64), dim3(256), 0, stream>>>(f_after, fT, 512, 512, 512L * 512, 512L * 512);
  k_transpose_cast<<<dim3(24, 8, 1), dim3(256), 0, stream>>>(gru_k, gruT, 512, 1536, 0L, 0L);
  k_conv<<<dim3(512), dim3(256), 0, stream>>>(xp, fT, za);
  k_gemm<<<dim3(1536), dim3(256), 0, stream>>>(xp, gruT, XM, 12, 1, 31, 0L, 1);
  k_dza<<<dim3(512), dim3(256), 0, stream>>>(za, f_skip, ug, dza);
  k_sent<<<dim3(4096), dim3(256), 0, stream>>>((u32*)hstep);
  k_rnn<<<dim3(64), dim3(256), 0, stream>>>(XM, dza, gru_rec, gru_bias, f_skip, hstep, out);
}

// Round 11
// 1944.813 us; speedup vs baseline: 1.0371x; 1.0371x over previous
//
#include <hip/hip_runtime.h>
#include <stdint.h>

typedef unsigned short u16;
typedef unsigned int   u32;
typedef __attribute__((ext_vector_type(8))) short short8;
typedef __attribute__((ext_vector_type(4))) float f32x4;
typedef __attribute__((ext_vector_type(4))) u32   u32x4;

#define AS1 __attribute__((address_space(1)))
#define AS3 __attribute__((address_space(3)))

#define SENT 0x7FC0u   // bf16 NaN sentinel: unreachable by f2bf of finite |h|<1.05
#define HS   528       // hBl batch-row stride in u16: 1056B -> 2-way banks (free)

__device__ __forceinline__ float bf2f(u16 u) {
  union { u32 i; float f; } v; v.i = ((u32)u) << 16; return v.f;
}
__device__ __forceinline__ u16 f2bf(float f) {
  union { float f; u32 i; } v; v.f = f;
  u32 i = v.i;
  i += 0x7FFFu + ((i >> 16) & 1u);   // round-to-nearest-even
  return (u16)(i >> 16);
}
__device__ __forceinline__ float tanh_fast(float x) {
  const float e = __expf(-2.f * fabsf(x));
  const float t = (1.f - e) / (1.f + e);
  return __builtin_copysignf(t, x);
}

__device__ __forceinline__ void gload16(const u16* src, u16* ldsDst) {
  __builtin_amdgcn_global_load_lds((const AS1 u32*)src, (AS3 u32*)ldsDst, 16, 0, 0);
}

// ---- MALL-coherent (cache-bypassing) h exchange — PROVEN protocol ----------
__device__ __forceinline__ short8 ldg_sc_h_wait(const u16* p) {
  short8 r;
  asm volatile("global_load_dwordx4 %0, %1, off sc0 sc1\n\t"
               "s_waitcnt vmcnt(0)"
               : "=v"(r) : "v"(p) : "memory");
  return r;
}
__device__ __forceinline__ void stg_sc_h(u16* p, u16 v) {
  asm volatile("global_store_short %0, %1, off sc0 sc1" :: "v"(p), "v"((u32)v) : "memory");
}

// ---------------- init: pad+cast x ------------------------------------------
__global__ void k_init(const float* __restrict__ x, u16* __restrict__ xp) {
  const long NXP = 32L * 576 * 512;
  long i0 = (long)blockIdx.x * 256 + threadIdx.x;
  for (long i = i0; i < NXP; i += (long)gridDim.x * 256) {
    long b = i / (576 * 512);
    int rem = (int)(i - b * (576 * 512));
    int rr = rem >> 9, dd = rem & 511;
    int t = rr - 31;                       // SAME pad: 31 left, 33 right
    float v = (t >= 0 && t < 512) ? x[(b * 512 + t) * 512 + dd] : 0.f;
    xp[i] = f2bf(v);
  }
}

// ---------------- sentinel fill of hstep (16.77 MB) --------------------------
__global__ void k_sent(u32* __restrict__ hs) {
  const u32x4 s = u32x4{(SENT << 16) | SENT, (SENT << 16) | SENT,
                        (SENT << 16) | SENT, (SENT << 16) | SENT};
  *(u32x4*)&hs[((long)blockIdx.x * 256 + threadIdx.x) * 4] = s;
}

// ---------------- transpose + cast fp32 -> bf16 ------------------------------
__global__ void k_transpose_cast(const float* __restrict__ in, u16* __restrict__ out,
                                 int rows, int cols, long inWStride, long outWStride) {
  __shared__ float tile[64][65];
  const int w = blockIdx.z;
  const float* ip = in + (long)w * inWStride;
  u16* op = out + (long)w * outWStride;
  const int r0 = blockIdx.y * 64, c0 = blockIdx.x * 64;
  const int tr = threadIdx.x >> 6, tc = threadIdx.x & 63;
  #pragma unroll
  for (int p = 0; p < 16; ++p) {
    int rr = p * 4 + tr;
    tile[rr][tc] = ip[(long)(r0 + rr) * cols + c0 + tc];
  }
  __syncthreads();
  #pragma unroll
  for (int p = 0; p < 16; ++p) {
    int rr = p * 4 + tr;
    op[(long)(c0 + rr) * rows + r0 + tc] = f2bf(tile[tc][rr]);
  }
}

// ---------------- conv GEMM: M=256 tile, counted-vmcnt pipeline, T2 swizzle --
// z[row, h] = sum_w sum_d xp[row+w, d] * fT[w, h, d].
// 256 blocks (1/CU, 128KB LDS). A panel 320x64 double-buffered (staged once per
// dsub); B triple-buffered, staged 2 phases ahead. Raw s_barrier + counted
// vmcnt (never 0 in steady state). XOR-swizzled LDS via pre-swizzled source.
__global__ __launch_bounds__(256, 1) void k_conv(
    const u16* __restrict__ A, const u16* __restrict__ Bm, u16* __restrict__ C)
{
  __shared__ __align__(16) u16 Abig[2][320 * 64];   // 80 KB
  __shared__ __align__(16) u16 Blds[3][128 * 64];   // 48 KB
  const int bid0 = blockIdx.x;
  const int bid = (bid0 & 7) * 32 + (bid0 >> 3);    // XCD-bijective (256 % 8 == 0)
  const int mt = bid & 63, nt = bid >> 6;           // same-B blocks share an XCD chunk
  const int h0 = nt * 128;
  const int b = mt >> 1;
  const int t0 = (mt & 1) * 256;
  const long row0 = (long)mt * 256;
  const int tid = threadIdx.x;
  const int wv = tid >> 6, l = tid & 63;
  const int wr = wv >> 1, wc = wv & 1;              // 2M x 2N wave grid
  const int sRow = wv * 8 + (l >> 3);
  const int sColSw = ((l & 7) ^ (l >> 3)) * 8;      // source-swizzled col (elems)
  f32x4 acc[8][4];
  #pragma unroll
  for (int m = 0; m < 8; ++m)
    #pragma unroll
    for (int n = 0; n < 4; ++n) acc[m][n] = f32x4{0.f, 0.f, 0.f, 0.f};

  const long aRow0 = (long)b * 576 + t0;            // 320 rows fit pitch 576 exactly

  auto stageA = [&](int d) {
    const int dcol = d << 6;
    #pragma unroll
    for (int c = 0; c < 10; ++c)
      gload16(A + (aRow0 + c * 32 + sRow) * 512 + dcol + sColSw,
              &Abig[d & 1][(c * 32 + wv * 8) * 64]);
  };
  auto stageB = [&](int p) {
    const int d = p >> 6, w = p & 63;
    const u16* bB = Bm + ((long)w << 18) + (long)h0 * 512 + (d << 6) + sColSw;
    #pragma unroll
    for (int c = 0; c < 4; ++c)
      gload16(bB + (long)(c * 32 + sRow) * 512, &Blds[p % 3][(c * 32 + wv * 8) * 64]);
  };

  stageA(0); stageB(0); stageB(1);                  // prologue (18 loads in flight)
  for (int p = 0; p < 512; ++p) {
    const int d = p >> 6, w = p & 63;
    if (p + 2 < 512) stageB(p + 2);
    if (w == 0 && d < 7) stageA(d + 1);
    // Counted wait: N = count of loads YOUNGER than the ones phase p consumes.
    // w<=2 & d<7: {B(p+1),B(p+2),A(d+1)}=18. Else steady {B(p+1),B(p+2)}=8
    // (A drained at w==3 since it is older than B(p)). Tail: 0.
    if (p >= 510)              asm volatile("s_waitcnt vmcnt(0)"  ::: "memory");
    else if (w <= 2 && d < 7)  asm volatile("s_waitcnt vmcnt(18)" ::: "memory");
    else                       asm volatile("s_waitcnt vmcnt(8)"  ::: "memory");
    __builtin_amdgcn_s_barrier();                   // all waves' p-loads in LDS
    __builtin_amdgcn_sched_barrier(0);
    const u16* Ab = &Abig[d & 1][0];
    const u16* Bb = &Blds[p % 3][0];
    #pragma unroll
    for (int kk = 0; kk < 2; ++kk) {
      short8 af[8], bf[4];
      #pragma unroll
      for (int m = 0; m < 8; ++m) {
        const int row = w + wr * 128 + m * 16 + (l & 15);
        const int ci = (kk * 32 + (l >> 4) * 8) ^ ((row & 7) * 8);
        af[m] = *(const short8*)&Ab[row * 64 + ci];
      }
      #pragma unroll
      for (int n = 0; n < 4; ++n) {
        const int row = wc * 64 + n * 16 + (l & 15);
        const int ci = (kk * 32 + (l >> 4) * 8) ^ ((row & 7) * 8);
        bf[n] = *(const short8*)&Bb[row * 64 + ci];
      }
      #pragma unroll
      for (int m = 0; m < 8; ++m)
        #pragma unroll
        for (int n = 0; n < 4; ++n)
          acc[m][n] = __builtin_amdgcn_mfma_f32_16x16x32_bf16(af[m], bf[n], acc[m][n], 0, 0, 0);
    }
    __builtin_amdgcn_s_barrier();                   // readers done before overwrite
  }
  const int lr = (l >> 4) * 4, lc = l & 15;
  #pragma unroll
  for (int m = 0; m < 8; ++m)
    #pragma unroll
    for (int n = 0; n < 4; ++n)
      #pragma unroll
      for (int r = 0; r < 4; ++r) {
        const long row = row0 + wr * 128 + m * 16 + lr + r;   // = b*512 + t
        const int col = h0 + wc * 64 + n * 16 + lc;
        C[row * 512 + col] = f2bf(tanhf(acc[m][n][r]));
      }
}

// ---------------- tiled MFMA GEMM (XM = x @ gru_kernel) ----------------------
__global__ __launch_bounds__(256) void k_gemm(
    const u16* __restrict__ A, const u16* __restrict__ Bm, u16* __restrict__ C,
    int nTiles, int kw, int woff, long bWStride, int outMode)
{
  __shared__ __align__(16) u16 Alds[128 * 64];
  __shared__ __align__(16) u16 Blds[128 * 64];
  const int bid0 = blockIdx.x;
  const int cpx = gridDim.x >> 3;
  const int bid = (bid0 & 7) * cpx + (bid0 >> 3);
  const int mt = bid / nTiles, nt = bid - mt * nTiles;
  const int bb = (mt * 128) >> 9;
  const int t0 = (mt * 128) & 511;
  const int h0 = nt * 128;
  const int tid = threadIdx.x;
  const int wv = tid >> 6, l = tid & 63;
  const int wr = wv >> 1, wc = wv & 1;
  const int sRow = wv * 8 + (l >> 3);
  const int sCol = (l & 7) * 8;
  f32x4 acc[4][4];
  #pragma unroll
  for (int m = 0; m < 4; ++m)
    #pragma unroll
    for (int n = 0; n < 4; ++n) acc[m][n] = f32x4{0.f, 0.f, 0.f, 0.f};

  const int kIters = kw * 8;
  const long aRow0 = (long)(bb * 576 + t0 + woff);
  for (int q = 0; q < kIters; ++q) {
    const int w = q >> 3, dsub = (q & 7) << 6;
    const u16* aB = A + (aRow0 + w) * 512 + dsub + sCol;
    const u16* bB = Bm + (long)w * bWStride + (long)h0 * 512 + dsub + sCol;
    __syncthreads();
    #pragma unroll
    for (int c = 0; c < 4; ++c) {
      gload16(aB + (long)(c * 32 + sRow) * 512, &Alds[c * 2048 + wv * 512]);
      gload16(bB + (long)(c * 32 + sRow) * 512, &Blds[c * 2048 + wv * 512]);
    }
    __syncthreads();
    #pragma unroll
    for (int kk = 0; kk < 2; ++kk) {
      short8 af[4], bf[4];
      #pragma unroll
      for (int m = 0; m < 4; ++m)
        af[m] = *(const short8*)&Alds[(wr * 64 + m * 16 + (l & 15)) * 64 + kk * 32 + (l >> 4) * 8];
      #pragma unroll
      for (int n = 0; n < 4; ++n)
        bf[n] = *(const short8*)&Blds[(wc * 64 + n * 16 + (l & 15)) * 64 + kk * 32 + (l >> 4) * 8];
      #pragma unroll
      for (int m = 0; m < 4; ++m)
        #pragma unroll
        for (int n = 0; n < 4; ++n)
          acc[m][n] = __builtin_amdgcn_mfma_f32_16x16x32_bf16(af[m], bf[n], acc[m][n], 0, 0, 0);
    }
  }
  const int lr = (l >> 4) * 4, lc = l & 15;
  #pragma unroll
  for (int m = 0; m < 4; ++m)
    #pragma unroll
    for (int n = 0; n < 4; ++n)
      #pragma unroll
      for (int r = 0; r < 4; ++r) {
        const int row = mt * 128 + wr * 64 + m * 16 + lr + r;
        const int col = h0 + wc * 64 + n * 16 + lc;
        const float v = acc[m][n][r];
        if (outMode == 0) {
          C[(long)row * 512 + col] = f2bf(tanhf(v));
        } else {
          const int b = row >> 9, t = row & 511;
          C[((long)t * 32 + b) * 1536 + col] = f2bf(v);
        }
      }
}

// ---------------- dza[t][b] = za(b,t,:)·wd2 + (g1-g0) -----------------------
__global__ void k_dza(const u16* __restrict__ za, const float* __restrict__ fskip,
                      const float* __restrict__ ug, float* __restrict__ dza) {
  __shared__ float wd2[512];
  const int t = blockIdx.x, tid = threadIdx.x;
  for (int i = tid; i < 512; i += 256) wd2[i] = fskip[(512 + i) * 2 + 1] - fskip[(512 + i) * 2];
  __syncthreads();
  const int b = tid >> 3, seg = (tid & 7) * 64;
  const u16* row = za + ((long)b * 512 + t) * 512 + seg;
  float pp = 0.f;
  #pragma unroll
  for (int j = 0; j < 8; ++j) {
    short8 v = *(const short8*)&row[j * 8];
    #pragma unroll
    for (int e = 0; e < 8; ++e) pp += bf2f((u16)v[e]) * wd2[seg + j * 8 + e];
  }
  pp += __shfl_xor(pp, 1); pp += __shfl_xor(pp, 2); pp += __shfl_xor(pp, 4);
  if ((tid & 7) == 0) {
    float u0 = ug[((long)t * 32 + b) * 2 + 0], u1 = ug[((long)t * 32 + b) * 2 + 1];
    float g0 = -logf(-logf(u0 + 1e-20f) + 1e-20f);
    float g1 = -logf(-logf(u1 + 1e-20f) + 1e-20f);
    dza[t * 32 + b] = pp + (g1 - g0);
  }
}

// ---------------- persistent recurrence: 8 domains x 8 slices ---------------
// EXACT round-7 protocol (proven 1273 us). DO NOT TOUCH.
__global__ __launch_bounds__(256, 1) void k_rnn(
    const u16* __restrict__ XM, const float* __restrict__ dza,
    const float* __restrict__ Wrec, const float* __restrict__ gbias,
    const float* __restrict__ fskip, u16* hstep, float* __restrict__ out)
{
  const int bid = blockIdx.x, d = bid & 7, s = bid >> 3;
  const int tid = threadIdx.x, wv = tid >> 6, l = tid & 63;
  __shared__ __align__(16) u16 hBl[2][4 * HS];
  __shared__ float s1s[2][4];

  float wdv[8];
  #pragma unroll
  for (int e = 0; e < 8; ++e)
    wdv[e] = fskip[(l * 8 + e) * 2 + 1] - fskip[(l * 8 + e) * 2];

  const int colb = s * 64 + wv * 16 + (l & 15);
  const int kq = (l >> 4) * 8;

  short8 wf[3][16];
  #pragma unroll
  for (int g = 0; g < 3; ++g)
    #pragma unroll
    for (int kk = 0; kk < 16; ++kk) {
      short8 tmp;
      #pragma unroll
      for (int e = 0; e < 8; ++e)
        tmp[e] = (short)f2bf(Wrec[(long)(kk * 32 + kq + e) * 1536 + g * 512 + colb]);
      wf[g][kk] = tmp;
    }
  float bi[3], br[3];
  #pragma unroll
  for (int g = 0; g < 3; ++g) {
    bi[g] = gbias[g * 512 + colb];
    br[g] = gbias[1536 + g * 512 + colb];
  }
  const int myb = d * 4;
  float hp[4] = {0.f, 0.f, 0.f, 0.f};
  float hnv[4] = {0.f, 0.f, 0.f, 0.f};

  u16 xmc[3][4];
  float dzc;
  if (l < 16) {
    const u16* xr = XM + (long)myb * 1536;
    #pragma unroll
    for (int r = 0; r < 4; ++r)
      #pragma unroll
      for (int g = 0; g < 3; ++g)
        xmc[g][r] = xr[(long)r * 1536 + g * 512 + colb];
  }
  dzc = dza[myb + wv];

  for (int t = 0; t < 512; ++t) {
    const int p = t & 1;

    short8 h8;
    if (t > 0) {
      const u16* ph = hstep + ((long)(t - 1) * 32 + myb + wv) * 512 + l * 8;
      h8 = ldg_sc_h_wait(ph);
      bool bad = true;
      while (bad) {
        bad = false;
        #pragma unroll
        for (int e = 0; e < 8; ++e) bad |= ((u16)h8[e] == SENT);
        if (bad) h8 = ldg_sc_h_wait(ph);
      }
    } else {
      #pragma unroll
      for (int e = 0; e < 8; ++e) h8[e] = 0;
    }

    if (t > 0 && l < 16) {
      #pragma unroll
      for (int r = 0; r < 4; ++r)
        out[((long)(myb + r) * 512 + (t - 1)) * 512 + colb] = hnv[r];
    }

    u16 xmn[3][4];
    const int tn = (t < 511) ? t + 1 : t;
    if (l < 16) {
      const u16* xr = XM + ((long)tn * 32 + myb) * 1536;
      #pragma unroll
      for (int r = 0; r < 4; ++r)
        #pragma unroll
        for (int g = 0; g < 3; ++g)
          xmn[g][r] = xr[(long)r * 1536 + g * 512 + colb];
    }
    const float dzn = dza[tn * 32 + myb + wv];

    *(short8*)&hBl[p][wv * HS + l * 8] = h8;
    float pp = 0.f;
    #pragma unroll
    for (int e = 0; e < 8; ++e) pp += bf2f((u16)h8[e]) * wdv[e];
    #pragma unroll
    for (int o = 1; o < 64; o <<= 1) pp += __shfl_xor(pp, o);
    if (l == 0) s1s[p][wv] = 1.f / (1.f + __expf(-(pp + dzc)));
    __syncthreads();

    f32x4 acc[3];
    acc[0] = f32x4{0.f, 0.f, 0.f, 0.f}; acc[1] = acc[0]; acc[2] = acc[0];
    const int b4 = l & 3;
    #pragma unroll
    for (int kk = 0; kk < 16; ++kk) {
      short8 a = *(const short8*)&hBl[p][b4 * HS + kk * 32 + kq];
      acc[0] = __builtin_amdgcn_mfma_f32_16x16x32_bf16(a, wf[0][kk], acc[0], 0, 0, 0);
      acc[1] = __builtin_amdgcn_mfma_f32_16x16x32_bf16(a, wf[1][kk], acc[1], 0, 0, 0);
      acc[2] = __builtin_amdgcn_mfma_f32_16x16x32_bf16(a, wf[2][kk], acc[2], 0, 0, 0);
    }

    if (l < 16) {
      #pragma unroll
      for (int r = 0; r < 4; ++r) {
        const float xz = bf2f(xmc[0][r]) + bi[0];
        const float xr_ = bf2f(xmc[1][r]) + bi[1];
        const float xh = bf2f(xmc[2][r]) + bi[2];
        const float hz = acc[0][r] + br[0];
        const float hr = acc[1][r] + br[1];
        const float hh = acc[2][r] + br[2];
        const float z  = 1.f / (1.f + __expf(-(xz + hz)));
        const float rr = 1.f / (1.f + __expf(-(xr_ + hr)));
        const float hc = tanh_fast(xh + rr * hh);
        const float ht = z * hp[r] + (1.f - z) * hc;
        const float s1 = s1s[p][r];
        const float hn = hp[r] + s1 * (ht - hp[r]);
        stg_sc_h(&hstep[((long)t * 32 + myb + r) * 512 + colb], f2bf(hn));
        hp[r] = hn;
        hnv[r] = hn;
      }
      #pragma unroll
      for (int g = 0; g < 3; ++g)
        #pragma unroll
        for (int r = 0; r < 4; ++r) xmc[g][r] = xmn[g][r];
    }
    dzc = dzn;
  }
  if (l < 16) {
    #pragma unroll
    for (int r = 0; r < 4; ++r)
      out[((long)(myb + r) * 512 + 511) * 512 + colb] = hnv[r];
  }
}

// -----------------------------------------------------------------------------
extern "C" void kernel_launch(void* const* d_in, const int* in_sizes, int n_in,
                              void* d_out, int out_size, void* d_ws, size_t ws_size,
                              hipStream_t stream) {
  (void)in_sizes; (void)n_in; (void)out_size; (void)ws_size;
  const float* x        = (const float*)d_in[0];
  const float* f_after  = (const float*)d_in[1];
  const float* f_skip   = (const float*)d_in[2];
  const float* gru_k    = (const float*)d_in[3];
  const float* gru_rec  = (const float*)d_in[4];
  const float* gru_bias = (const float*)d_in[5];
  const float* ug       = (const float*)d_in[6];
  float* out = (float*)d_out;

  char* ws = (char*)d_ws;
  size_t off = 0;
  auto alloc = [&](size_t bytes) { void* p = ws + off; off = (off + bytes + 255) & ~(size_t)255; return p; };
  u16*  xp    = (u16*)alloc(32L * 576 * 512 * 2);
  u16*  fT    = (u16*)alloc(64L * 512 * 512 * 2);
  u16*  gruT  = (u16*)alloc(1536L * 512 * 2);
  u16*  za    = (u16*)alloc(32L * 512 * 512 * 2);   // reused as hstep after k_dza
  u16*  XM    = (u16*)alloc(512L * 32 * 1536 * 2);
  float* dza  = (float*)alloc(512L * 32 * 4);
  u16*  hstep = za;                                  // [512][32][512] bf16

  k_init<<<dim3(4096), dim3(256), 0, stream>>>(x, xp);
  k_transpose_cast<<<dim3(8, 8, 64), dim3(256), 0, stream>>>(f_after, fT, 512, 512, 512L * 512, 512L * 512);
  k_transpose_cast<<<dim3(24, 8, 1), dim3(256), 0, stream>>>(gru_k, gruT, 512, 1536, 0L, 0L);
  k_conv<<<dim3(256), dim3(256), 0, stream>>>(xp, fT, za);
  k_gemm<<<dim3(1536), dim3(256), 0, stream>>>(xp, gruT, XM, 12, 1, 31, 0L, 1);
  k_dza<<<dim3(512), dim3(256), 0, stream>>>(za, f_skip, ug, dza);
  k_sent<<<dim3(4096), dim3(256), 0, stream>>>((u32*)hstep);
  k_rnn<<<dim3(64), dim3(256), 0, stream>>>(XM, dza, gru_rec, gru_bias, f_skip, hstep, out);
}